// Round 21
// baseline (104.463 us; speedup 1.0000x reference)
//
#include <hip/hip_runtime.h>
#include <hip/hip_bf16.h>

typedef __attribute__((ext_vector_type(8))) short bf16x8;
typedef __attribute__((ext_vector_type(4))) float f32x4;
typedef __attribute__((ext_vector_type(16))) float f32x16;
typedef __attribute__((ext_vector_type(4))) unsigned int u32x4;

#define MFMA16(a, b, c) __builtin_amdgcn_mfma_f32_16x16x32_bf16((a), (b), (c), 0, 0, 0)
#define MFMA32(a, b, c) __builtin_amdgcn_mfma_f32_32x32x16_bf16((a), (b), (c), 0, 0, 0)

static constexpr int BATCH = 4, S = 2048, DMODEL = 512, H = 8, HD = 64;
static constexpr int M = BATCH * S;  // 8192

#define WAIT_VM(N) asm volatile("s_waitcnt vmcnt(" #N ")" ::: "memory")
#define SCHEDB() __builtin_amdgcn_sched_barrier(0)

__device__ __forceinline__ float rexp2(float x) {  // raw v_exp_f32
  float r;
  asm("v_exp_f32 %0, %1" : "=v"(r) : "v"(x));
  return r;
}

// round-to-nearest-even f32 -> bf16
__device__ __forceinline__ short f2b(float f) {
  unsigned int u = __builtin_bit_cast(unsigned int, f);
  unsigned int r = (u + 0x7fffu + ((u >> 16) & 1u)) >> 16;
  return (short)r;
}

__device__ __forceinline__ bf16x8 cvt8(const float4& a, const float4& b) {
  bf16x8 r;
  r[0] = f2b(a.x); r[1] = f2b(a.y); r[2] = f2b(a.z); r[3] = f2b(a.w);
  r[4] = f2b(b.x); r[5] = f2b(b.y); r[6] = f2b(b.z); r[7] = f2b(b.w);
  return r;
}

// async global -> LDS, 16 bytes/lane
__device__ __forceinline__ void glds16(const void* g, void* l) {
  __builtin_amdgcn_global_load_lds(
      (const __attribute__((address_space(1))) unsigned int*)g,
      (__attribute__((address_space(3))) unsigned int*)l, 16, 0, 0);
}

// ---------------- weight fp32 -> bf16 (weights only; activations fused into proj) ----------------
__global__ __launch_bounds__(256) void convert_w(
    const float* __restrict__ Wq, const float* __restrict__ Wk,
    const float* __restrict__ Wv, const float* __restrict__ Wo,
    short* __restrict__ Wb) {
  const float* src = (blockIdx.y == 0) ? Wq : (blockIdx.y == 1) ? Wk
                   : (blockIdx.y == 2) ? Wv : Wo;
  short* dst = Wb + blockIdx.y * (DMODEL * DMODEL);
  int i = (blockIdx.x * 256 + threadIdx.x) * 8;
  float4 a = *(const float4*)&src[i];
  float4 b = *(const float4*)&src[i + 4];
  *(bf16x8*)&dst[i] = cvt8(a, b);
}

// ---------------- fused Q/K/V projection: C = A(fp32) @ W^T + b ----------------
// A staged as fp32 via glds (16KB/tile, XOR-swizzled by row&7), converted to bf16
// in-register at fragment read (bit-identical to the old convert pass). A and B
// both 3-ring, 2-deep, 6 glds/tile/wave, vmcnt(6). V via swapped operands (C^T).
// NOTE: SM is char-indexed; B dests are w*1024 (R20 bug: w*512 overlapped waves).
__global__ __launch_bounds__(256) void proj_gemm(
    const float* __restrict__ Aq, const float* __restrict__ Ak, const float* __restrict__ Av,
    const short* __restrict__ Wb,
    const float* __restrict__ bq, const float* __restrict__ bk, const float* __restrict__ bv,
    short* __restrict__ Qp, short* __restrict__ Kp, short* __restrict__ Vp) {
  const int which = blockIdx.y;
  const float* A    = (which == 0) ? Aq : (which == 1) ? Ak : Av;
  const short* W    = Wb + which * (DMODEL * DMODEL);
  const float* bias = (which == 0) ? bq : (which == 1) ? bk : bv;
  short* dst        = (which == 0) ? Qp : (which == 1) ? Kp : Vp;

  const int tm = blockIdx.x & 63;
  const int tn = blockIdx.x >> 6;
  const int m0 = tm * 128, n0 = tn * 128;
  const int t = threadIdx.x;
  const int lane = t & 63, w = t >> 6;
  const int g = lane >> 4, c = lane & 15;
  const int wr = w >> 1, wc = w & 1;

  __shared__ __align__(16) char SM[3][24576];  // [buf][A fp32 16KB | B bf16 8KB] = 72KB

  f32x4 acc[4][4];
  const f32x4 fz = {0.f, 0.f, 0.f, 0.f};
#pragma unroll
  for (int i = 0; i < 4; ++i)
#pragma unroll
    for (int j = 0; j < 4; ++j) acc[i][j] = fz;

  // A staging (fp32): wave w, j=0..3 -> LDS bytes [w*4096 + j*1024, +1024); row =
  // w*32+j*8+(lane>>3), src granule = (lane&7) ^ (lane>>3)  [row&7 == lane>>3]
  const float* Asrc[4];
#pragma unroll
  for (int j = 0; j < 4; ++j)
    Asrc[j] = A + (m0 + w * 32 + j * 8 + (lane >> 3)) * DMODEL +
              (((lane & 7) ^ (lane >> 3)) * 4);
  // B staging (bf16, linear): rows w*16+(lane>>2) and +64; 64 B/row
  const short* Bsrc0 = W + (n0 + w * 16 + (lane >> 2)) * DMODEL + (lane & 3) * 8;
  const short* Bsrc1 = Bsrc0 + 64 * DMODEL;

  // prologue: tiles 0 and 1 (6 glds each: A 4 + B 2)
#pragma unroll
  for (int tt = 0; tt < 2; ++tt) {
#pragma unroll
    for (int j = 0; j < 4; ++j)
      glds16(Asrc[j] + tt * 32, &SM[tt][w * 4096 + j * 1024]);
    glds16(Bsrc0 + tt * 32, &SM[tt][16384 + w * 1024]);
    glds16(Bsrc1 + tt * 32, &SM[tt][16384 + 4096 + w * 1024]);
  }

  int ob0 = 0, ob1 = 1, ob2 = 2;
  for (int kt = 0; kt < 16; ++kt) {
    if (kt == 15) { WAIT_VM(0); } else { WAIT_VM(6); }
    __builtin_amdgcn_s_barrier();
    SCHEDB();
    if (kt < 14) {
      const int k0 = (kt + 2) * 32;
#pragma unroll
      for (int j = 0; j < 4; ++j)
        glds16(Asrc[j] + k0, &SM[ob2][w * 4096 + j * 1024]);
      glds16(Bsrc0 + k0, &SM[ob2][16384 + w * 1024]);
      glds16(Bsrc1 + k0, &SM[ob2][16384 + 4096 + w * 1024]);
    }
    SCHEDB();

    bf16x8 af[4], bfr[4];
#pragma unroll
    for (int i = 0; i < 4; ++i) {
      const int row = wr * 64 + i * 16 + c;
      const int key = row & 7;
      const float4 f0 = *(const float4*)&SM[ob0][row * 128 + ((g * 2) ^ key) * 16];
      const float4 f1 = *(const float4*)&SM[ob0][row * 128 + ((g * 2 + 1) ^ key) * 16];
      af[i] = cvt8(f0, f1);
    }
#pragma unroll
    for (int j = 0; j < 4; ++j) {
      const int row = wc * 64 + j * 16 + c;
      bfr[j] = *(const bf16x8*)&SM[ob0][16384 + row * 64 + g * 16];
    }
    if (which == 2) {
#pragma unroll
      for (int i = 0; i < 4; ++i)
#pragma unroll
        for (int j = 0; j < 4; ++j)
          acc[i][j] = MFMA16(bfr[j], af[i], acc[i][j]);  // C^T blocks
    } else {
#pragma unroll
      for (int i = 0; i < 4; ++i)
#pragma unroll
        for (int j = 0; j < 4; ++j)
          acc[i][j] = MFMA16(af[i], bfr[j], acc[i][j]);
    }

    const int tmp = ob0; ob0 = ob1; ob1 = ob2; ob2 = tmp;
  }

  if (which == 2) {
    // acc = C^T: row n = n0+wc*64+j*16+g*4+r, col m = m0+wr*64+i*16+c
#pragma unroll
    for (int j = 0; j < 4; ++j) {
#pragma unroll
      for (int r = 0; r < 4; ++r) {
        const int n = n0 + wc * 64 + j * 16 + g * 4 + r;
        const int h = n >> 6, hd = n & 63;
        const float bn = bias[n];
#pragma unroll
        for (int i = 0; i < 4; ++i) {
          const int m = m0 + wr * 64 + i * 16 + c;
          const int bb = m >> 11, s = m & (S - 1);
          dst[((bb * H + h) * HD + hd) * S + s] = f2b(acc[i][j][r] + bn);
        }
      }
    }
  } else {
#pragma unroll
    for (int i = 0; i < 4; ++i) {
#pragma unroll
      for (int j = 0; j < 4; ++j) {
        const int n = n0 + wc * 64 + j * 16 + c;
        const int h = n >> 6, hd = n & 63;
        const float bn = bias[n];
#pragma unroll
        for (int r = 0; r < 4; ++r) {
          const int m = m0 + wr * 64 + i * 16 + g * 4 + r;
          const int bb = m >> 11, s = m & (S - 1);
          dst[((bb * H + h) * S + s) * HD + hd] = f2b(acc[i][j][r] + bn);
        }
      }
    }
  }
}

// ---------------- output GEMM: Out = att @ Wo^T + bo (fp32 out) ----------------
__global__ __launch_bounds__(256) void out_gemm(
    const short* __restrict__ Am, const short* __restrict__ W,
    const float* __restrict__ bias, float* __restrict__ Out) {
  const int tm = blockIdx.x & 63;
  const int tn = blockIdx.x >> 6;
  const int m0 = tm * 128, n0 = tn * 128;
  const int t = threadIdx.x;
  const int lane = t & 63, w = t >> 6;
  const int g = lane >> 4, c = lane & 15;
  const int wr = w >> 1, wc = w & 1;

  __shared__ __align__(16) short SM[4][2 * 128 * 32];  // 64 KB

  f32x4 acc[4][4];
  const f32x4 fz = {0.f, 0.f, 0.f, 0.f};
#pragma unroll
  for (int i = 0; i < 4; ++i)
#pragma unroll
    for (int j = 0; j < 4; ++j) acc[i][j] = fz;

  const short* Asrc0 = Am + (m0 + w * 16 + (lane >> 2)) * DMODEL + (lane & 3) * 8;
  const short* Asrc1 = Asrc0 + 64 * DMODEL;
  const short* Bsrc0 = W + (n0 + w * 16 + (lane >> 2)) * DMODEL + (lane & 3) * 8;
  const short* Bsrc1 = Bsrc0 + 64 * DMODEL;

#pragma unroll
  for (int tt = 0; tt < 3; ++tt) {
    glds16(Asrc0 + tt * 32, &SM[tt][w * 512]);
    glds16(Asrc1 + tt * 32, &SM[tt][2048 + w * 512]);
    glds16(Bsrc0 + tt * 32, &SM[tt][4096 + w * 512]);
    glds16(Bsrc1 + tt * 32, &SM[tt][4096 + 2048 + w * 512]);
  }

#pragma unroll 4
  for (int kt = 0; kt < 16; ++kt) {
    if (kt == 15) { WAIT_VM(0); } else if (kt == 14) { WAIT_VM(4); } else { WAIT_VM(8); }
    __builtin_amdgcn_s_barrier();
    SCHEDB();
    if (kt < 13) {
      const int k0 = (kt + 3) * 32;
      glds16(Asrc0 + k0, &SM[(kt + 3) & 3][w * 512]);
      glds16(Asrc1 + k0, &SM[(kt + 3) & 3][2048 + w * 512]);
      glds16(Bsrc0 + k0, &SM[(kt + 3) & 3][4096 + w * 512]);
      glds16(Bsrc1 + k0, &SM[(kt + 3) & 3][4096 + 2048 + w * 512]);
    }
    SCHEDB();

    bf16x8 af[4], bfr[4];
#pragma unroll
    for (int i = 0; i < 4; ++i)
      af[i] = *(const bf16x8*)&SM[kt & 3][(wr * 64 + i * 16 + c) * 32 + g * 8];
#pragma unroll
    for (int j = 0; j < 4; ++j)
      bfr[j] = *(const bf16x8*)&SM[kt & 3][4096 + (wc * 64 + j * 16 + c) * 32 + g * 8];
#pragma unroll
    for (int i = 0; i < 4; ++i)
#pragma unroll
      for (int j = 0; j < 4; ++j)
        acc[i][j] = MFMA16(af[i], bfr[j], acc[i][j]);
  }

#pragma unroll
  for (int i = 0; i < 4; ++i) {
#pragma unroll
    for (int j = 0; j < 4; ++j) {
      const int n = n0 + wc * 64 + j * 16 + c;
      const float bn = bias[n];
#pragma unroll
      for (int r = 0; r < 4; ++r) {
        const int m = m0 + wr * 64 + i * 16 + g * 4 + r;
        Out[m * DMODEL + n] = acc[i][j][r] + bn;
      }
    }
  }
}

// ---------------- flash attention (R19-proven): 8 waves = 4 q-subtiles x 2 kv-halves ----------------
__global__ __launch_bounds__(512, 4) void attn_kernel(
    const short* __restrict__ Qp, const short* __restrict__ Kp,
    const short* __restrict__ VTp, short* __restrict__ att) {
  const int bid = blockIdx.x;
  const int swzb = (bid & 7) * 64 + (bid >> 3);  // bijective (512 % 8 == 0)
  const int qt = swzb & 15;
  const int bh = swzb >> 4;
  const int b = bh >> 3, h = bh & 7;
  const short* Q  = Qp  + bh * (S * HD);
  const char*  Kg = (const char*)(Kp  + bh * (S * HD));
  const char*  Vg = (const char*)(VTp + bh * (HD * S));

  const int t = threadIdx.x;
  const int lane = t & 63, w = t >> 6;   // w 0..7
  const int qi = w >> 1, sj = w & 1;
  const int l31 = lane & 31, hi = lane >> 5;
  const int q0 = qt * 128 + qi * 32;

  __shared__ __align__(16) char smem[2 * 32768];  // [buf][K 16KB | V^T 16KB]

  // K staging (paired-row layout inverse)
  const char* ksrc[2];
#pragma unroll
  for (int j = 0; j < 2; ++j) {
    const int rj = w * 8 + j * 4 + (lane >> 4);
    const int tk = (lane & 15) ^ (rj & 15);
    const int kj = 2 * rj + (tk >> 3);
    ksrc[j] = Kg + kj * 128 + (tk & 7) * 16;
  }
  // V^T staging
  const char* vsrc[2];
#pragma unroll
  for (int j = 0; j < 2; ++j) {
    const int row = w * 8 + j * 4 + (lane >> 4);
    vsrc[j] = Vg + row * 4096 + (((lane & 15) ^ (row & 15)) * 16);
  }

  bf16x8 qf[4];
#pragma unroll
  for (int ks = 0; ks < 4; ++ks)
    qf[ks] = *(const bf16x8*)&Q[(q0 + l31) * HD + ks * 16 + hi * 8];

  f32x16 o0, o1, lsum, fz16;
#pragma unroll
  for (int i = 0; i < 16; ++i) { o0[i] = 0.f; o1[i] = 0.f; lsum[i] = 0.f; fz16[i] = 0.f; }

  const float SCL = 0.18033688011112042f;  // log2(e)/sqrt(HD)

  const int kbase = (l31 >> 1) * 256;
  const int k8 = (l31 & 1) << 3;
  const int kx = (l31 >> 1) & 15;
  const int vx = l31 & 15;
  const int sjb = sj * 8192;

  // prologue: stage tile 0 into buf 0 (4 glds/wave)
  {
    char* nb = smem;
#pragma unroll
    for (int j = 0; j < 2; ++j) glds16(ksrc[j], nb + w * 2048 + j * 1024);
#pragma unroll
    for (int j = 0; j < 2; ++j) glds16(vsrc[j], nb + 16384 + w * 2048 + j * 1024);
  }

  for (int kt = 0; kt < 16; ++kt) {
    WAIT_VM(0);  // tile kt landed
    __builtin_amdgcn_s_barrier();
    SCHEDB();
    if (kt < 15) {
      char* nb = smem + ((kt + 1) & 1) * 32768;
      const size_t ko = (size_t)(kt + 1) * 16384;
      const size_t vo = (size_t)(kt + 1) * 256;
#pragma unroll
      for (int j = 0; j < 2; ++j) glds16(ksrc[j] + ko, nb + w * 2048 + j * 1024);
#pragma unroll
      for (int j = 0; j < 2; ++j) glds16(vsrc[j] + vo, nb + 16384 + w * 2048 + j * 1024);
    }
    SCHEDB();

    const int cb = (kt & 1) * 32768;

    // ---- QK^T for this wave's kv-half ----
    f32x16 sA, sB;
    __builtin_amdgcn_s_setprio(1);
    {
      const int p0 = ((k8 | hi) ^ kx) * 16;
      sA = MFMA32(*(const bf16x8*)&smem[cb + sjb + kbase + p0],        qf[0], fz16);
      sB = MFMA32(*(const bf16x8*)&smem[cb + sjb + 4096 + kbase + p0], qf[0], fz16);
    }
#pragma unroll
    for (int ks = 1; ks < 4; ++ks) {
      const int p = ((k8 | (ks * 2 + hi)) ^ kx) * 16;
      sA = MFMA32(*(const bf16x8*)&smem[cb + sjb + kbase + p],        qf[ks], sA);
      sB = MFMA32(*(const bf16x8*)&smem[cb + sjb + 4096 + kbase + p], qf[ks], sB);
    }
    __builtin_amdgcn_s_setprio(0);

    // ---- P = exp2(score * SCL) ----
#pragma unroll
    for (int i = 0; i < 16; ++i) {
      sA[i] = rexp2(sA[i] * SCL);
      sB[i] = rexp2(sB[i] * SCL);
    }

    // ---- deferred denominator ----
#pragma unroll
    for (int i = 0; i < 16; ++i) lsum[i] += sA[i] + sB[i];

    // ---- P -> bf16 words ----
    unsigned int wrdA[8], wrdB[8];
#pragma unroll
    for (int i = 0; i < 8; ++i) {
      asm("v_cvt_pk_bf16_f32 %0, %1, %2" : "=v"(wrdA[i]) : "v"(sA[2 * i]), "v"(sA[2 * i + 1]));
      asm("v_cvt_pk_bf16_f32 %0, %1, %2" : "=v"(wrdB[i]) : "v"(sB[2 * i]), "v"(sB[2 * i + 1]));
    }

    // ---- PV over this kv-half ----
    __builtin_amdgcn_s_setprio(1);
#pragma unroll
    for (int ks = 0; ks < 4; ++ks) {
      const int ss = sj * 4 + ks;
      const int i0 = (ks & 1) * 4;
      const unsigned int* lo = (ks < 2) ? wrdA : wrdB;
      unsigned int a0 = lo[i0 + 0], b0 = lo[i0 + 2];
      unsigned int a1 = lo[i0 + 1], b1 = lo[i0 + 3];
      asm("v_permlane32_swap_b32 %0, %1" : "+v"(a0), "+v"(b0));
      asm("v_permlane32_swap_b32 %0, %1" : "+v"(a1), "+v"(b1));
      u32x4 fw;
      fw[0] = a0; fw[1] = a1; fw[2] = b0; fw[3] = b1;
      const bf16x8 pfrag = __builtin_bit_cast(bf16x8, fw);
      const int pv = ((ss * 2 + hi) ^ vx) * 16;
      const bf16x8 va0 = *(const bf16x8*)&smem[cb + 16384 + l31 * 256 + pv];
      const bf16x8 va1 = *(const bf16x8*)&smem[cb + 16384 + (32 + l31) * 256 + pv];
      o0 = MFMA32(va0, pfrag, o0);
      o1 = MFMA32(va1, pfrag, o1);
    }
    __builtin_amdgcn_s_setprio(0);
  }

  // ---- finalize denominator ----
  float ts[8];
#pragma unroll
  for (int i = 0; i < 8; ++i) ts[i] = lsum[i] + lsum[i + 8];
#pragma unroll
  for (int i = 0; i < 4; ++i) ts[i] = ts[i] + ts[i + 4];
  float lst = (ts[0] + ts[2]) + (ts[1] + ts[3]);
  lst += __shfl_xor(lst, 32, 64);

  // ---- merge kv-halves (pure sum) ----
  __syncthreads();
  float* mrg = (float*)smem;
  if (sj == 1) {
    float* p = mrg + (qi * 64 + lane) * 33;
#pragma unroll
    for (int i = 0; i < 16; ++i) { p[i] = o0[i]; p[16 + i] = o1[i]; }
    p[32] = lst;
  }
  __syncthreads();
  if (sj == 0) {
    const float* p = mrg + (qi * 64 + lane) * 33;
    const float inv = 1.0f / (lst + p[32]);
    short* arow = att + (b * S + q0 + l31) * DMODEL + h * HD;
#pragma unroll
    for (int dt = 0; dt < 2; ++dt) {
#pragma unroll
      for (int rr = 0; rr < 4; ++rr) {
        const int i0 = 4 * rr;
        const float* po = p + dt * 16;
        float v0 = ((dt ? o1[i0 + 0] : o0[i0 + 0]) + po[i0 + 0]) * inv;
        float v1 = ((dt ? o1[i0 + 1] : o0[i0 + 1]) + po[i0 + 1]) * inv;
        float v2 = ((dt ? o1[i0 + 2] : o0[i0 + 2]) + po[i0 + 2]) * inv;
        float v3 = ((dt ? o1[i0 + 3] : o0[i0 + 3]) + po[i0 + 3]) * inv;
        unsigned int w0, w1;
        asm("v_cvt_pk_bf16_f32 %0, %1, %2" : "=v"(w0) : "v"(v0), "v"(v1));
        asm("v_cvt_pk_bf16_f32 %0, %1, %2" : "=v"(w1) : "v"(v2), "v"(v3));
        uint2 pk2;
        pk2.x = w0; pk2.y = w1;
        *(uint2*)&arow[dt * 32 + rr * 8 + hi * 4] = pk2;
      }
    }
  }
}

extern "C" void kernel_launch(void* const* d_in, const int* in_sizes, int n_in,
                              void* d_out, int out_size, void* d_ws, size_t ws_size,
                              hipStream_t stream) {
  const float* query = (const float*)d_in[0];
  const float* key_  = (const float*)d_in[1];
  const float* value = (const float*)d_in[2];
  const float* Wq = (const float*)d_in[3];
  const float* bq = (const float*)d_in[4];
  const float* Wk = (const float*)d_in[5];
  const float* bk = (const float*)d_in[6];
  const float* Wv = (const float*)d_in[7];
  const float* bv = (const float*)d_in[8];
  const float* Wo = (const float*)d_in[9];
  const float* bo = (const float*)d_in[10];
  float* out = (float*)d_out;

  char* ws = (char*)d_ws;
  const size_t WB_BYTES  = (size_t)4 * DMODEL * DMODEL * 2;  // 2 MiB
  const size_t MAT_BYTES = (size_t)M * DMODEL * 2;           // 8 MiB each
  short* Wb  = (short*)ws;
  short* Qp  = (short*)(ws + WB_BYTES);
  short* Kp  = (short*)(ws + WB_BYTES + MAT_BYTES);
  short* Vp  = (short*)(ws + WB_BYTES + 2 * MAT_BYTES);   // transposed [B,H,HD,S]
  short* att = (short*)(ws + WB_BYTES + 3 * MAT_BYTES);

  convert_w<<<dim3(128, 4), 256, 0, stream>>>(Wq, Wk, Wv, Wo, Wb);
  proj_gemm<<<dim3(256, 3), 256, 0, stream>>>(query, key_, value, Wb, bq, bk, bv, Qp, Kp, Vp);
  attn_kernel<<<dim3(512), 512, 0, stream>>>(Qp, Kp, Vp, att);
  out_gemm<<<dim3(256), 256, 0, stream>>>(att, Wb + 3 * DMODEL * DMODEL, bo, out);
}

// Round 22
// 93.425 us; speedup vs baseline: 1.1181x; 1.1181x over previous
//
#include <hip/hip_runtime.h>
#include <hip/hip_bf16.h>

typedef __attribute__((ext_vector_type(8))) short bf16x8;
typedef __attribute__((ext_vector_type(4))) float f32x4;
typedef __attribute__((ext_vector_type(16))) float f32x16;
typedef __attribute__((ext_vector_type(4))) unsigned int u32x4;

#define MFMA16(a, b, c) __builtin_amdgcn_mfma_f32_16x16x32_bf16((a), (b), (c), 0, 0, 0)
#define MFMA32(a, b, c) __builtin_amdgcn_mfma_f32_32x32x16_bf16((a), (b), (c), 0, 0, 0)

static constexpr int BATCH = 4, S = 2048, DMODEL = 512, H = 8, HD = 64;
static constexpr int M = BATCH * S;  // 8192

#define WAIT_VM(N) asm volatile("s_waitcnt vmcnt(" #N ")" ::: "memory")
#define SCHEDB() __builtin_amdgcn_sched_barrier(0)

__device__ __forceinline__ float rexp2(float x) {  // raw v_exp_f32
  float r;
  asm("v_exp_f32 %0, %1" : "=v"(r) : "v"(x));
  return r;
}

// round-to-nearest-even f32 -> bf16
__device__ __forceinline__ short f2b(float f) {
  unsigned int u = __builtin_bit_cast(unsigned int, f);
  unsigned int r = (u + 0x7fffu + ((u >> 16) & 1u)) >> 16;
  return (short)r;
}

__device__ __forceinline__ bf16x8 cvt8(const float4& a, const float4& b) {
  bf16x8 r;
  r[0] = f2b(a.x); r[1] = f2b(a.y); r[2] = f2b(a.z); r[3] = f2b(a.w);
  r[4] = f2b(b.x); r[5] = f2b(b.y); r[6] = f2b(b.z); r[7] = f2b(b.w);
  return r;
}

// async global -> LDS, 16 bytes/lane
__device__ __forceinline__ void glds16(const void* g, void* l) {
  __builtin_amdgcn_global_load_lds(
      (const __attribute__((address_space(1))) unsigned int*)g,
      (__attribute__((address_space(3))) unsigned int*)l, 16, 0, 0);
}

// ---------------- fp32 -> bf16: activations (q,k,v) + weights ----------------
__global__ __launch_bounds__(256) void convert_all(
    const float* __restrict__ q, const float* __restrict__ k, const float* __restrict__ v,
    const float* __restrict__ Wq, const float* __restrict__ Wk,
    const float* __restrict__ Wv, const float* __restrict__ Wo,
    short* __restrict__ Abq, short* __restrict__ Abk, short* __restrict__ Abv,
    short* __restrict__ Wb) {
  const int bid = blockIdx.x;
  const float* src;
  short* dst;
  int i;
  if (bid < 6144) {
    const int which = bid >> 11;       // 0..2
    const int sub = bid & 2047;
    src = (which == 0) ? q : (which == 1) ? k : v;
    dst = (which == 0) ? Abq : (which == 1) ? Abk : Abv;
    i = (sub * 256 + threadIdx.x) * 8;
  } else {
    const int wb = bid - 6144;
    const int which = wb >> 7;         // 0..3
    const int sub = wb & 127;
    src = (which == 0) ? Wq : (which == 1) ? Wk : (which == 2) ? Wv : Wo;
    dst = Wb + which * (DMODEL * DMODEL);
    i = (sub * 256 + threadIdx.x) * 8;
  }
  float4 a = *(const float4*)&src[i];
  float4 b = *(const float4*)&src[i + 4];
  *(bf16x8*)&dst[i] = cvt8(a, b);
}

// ---------------- fused Q/K/V projection: C = Ab @ W^T + b (all-bf16, all-glds) ----------------
// R14-proven: 3-buf ring, vmcnt(4); V via swapped operands (C^T).
__global__ __launch_bounds__(256) void proj_gemm(
    const short* __restrict__ Abq, const short* __restrict__ Abk, const short* __restrict__ Abv,
    const short* __restrict__ Wb,
    const float* __restrict__ bq, const float* __restrict__ bk, const float* __restrict__ bv,
    short* __restrict__ Qp, short* __restrict__ Kp, short* __restrict__ Vp) {
  const int which = blockIdx.y;
  const short* A    = (which == 0) ? Abq : (which == 1) ? Abk : Abv;
  const short* W    = Wb + which * (DMODEL * DMODEL);
  const float* bias = (which == 0) ? bq : (which == 1) ? bk : bv;
  short* dst        = (which == 0) ? Qp : (which == 1) ? Kp : Vp;

  const int tm = blockIdx.x & 63;
  const int tn = blockIdx.x >> 6;
  const int m0 = tm * 128, n0 = tn * 128;
  const int t = threadIdx.x;
  const int lane = t & 63, w = t >> 6;
  const int g = lane >> 4, c = lane & 15;
  const int wr = w >> 1, wc = w & 1;

  __shared__ __align__(16) short SM[3][2 * 128 * 32];  // 48 KB

  f32x4 acc[4][4];
  const f32x4 fz = {0.f, 0.f, 0.f, 0.f};
#pragma unroll
  for (int i = 0; i < 4; ++i)
#pragma unroll
    for (int j = 0; j < 4; ++j) acc[i][j] = fz;

  const short* Asrc0 = A + (m0 + w * 16 + (lane >> 2)) * DMODEL + (lane & 3) * 8;
  const short* Asrc1 = Asrc0 + 64 * DMODEL;
  const short* Bsrc0 = W + (n0 + w * 16 + (lane >> 2)) * DMODEL + (lane & 3) * 8;
  const short* Bsrc1 = Bsrc0 + 64 * DMODEL;

#pragma unroll
  for (int tt = 0; tt < 2; ++tt) {
    glds16(Asrc0 + tt * 32, &SM[tt][w * 512]);
    glds16(Asrc1 + tt * 32, &SM[tt][2048 + w * 512]);
    glds16(Bsrc0 + tt * 32, &SM[tt][4096 + w * 512]);
    glds16(Bsrc1 + tt * 32, &SM[tt][4096 + 2048 + w * 512]);
  }

  int ob0 = 0, ob1 = 1, ob2 = 2;
  for (int kt = 0; kt < 16; ++kt) {
    if (kt == 15) { WAIT_VM(0); } else { WAIT_VM(4); }
    __builtin_amdgcn_s_barrier();
    SCHEDB();
    if (kt < 14) {
      const int k0 = (kt + 2) * 32;
      glds16(Asrc0 + k0, &SM[ob2][w * 512]);
      glds16(Asrc1 + k0, &SM[ob2][2048 + w * 512]);
      glds16(Bsrc0 + k0, &SM[ob2][4096 + w * 512]);
      glds16(Bsrc1 + k0, &SM[ob2][4096 + 2048 + w * 512]);
    }
    SCHEDB();

    bf16x8 af[4], bfr[4];
#pragma unroll
    for (int i = 0; i < 4; ++i)
      af[i] = *(const bf16x8*)&SM[ob0][(wr * 64 + i * 16 + c) * 32 + g * 8];
#pragma unroll
    for (int j = 0; j < 4; ++j)
      bfr[j] = *(const bf16x8*)&SM[ob0][4096 + (wc * 64 + j * 16 + c) * 32 + g * 8];
    if (which == 2) {
#pragma unroll
      for (int i = 0; i < 4; ++i)
#pragma unroll
        for (int j = 0; j < 4; ++j)
          acc[i][j] = MFMA16(bfr[j], af[i], acc[i][j]);  // C^T blocks
    } else {
#pragma unroll
      for (int i = 0; i < 4; ++i)
#pragma unroll
        for (int j = 0; j < 4; ++j)
          acc[i][j] = MFMA16(af[i], bfr[j], acc[i][j]);
    }

    const int tmp = ob0; ob0 = ob1; ob1 = ob2; ob2 = tmp;
  }

  if (which == 2) {
#pragma unroll
    for (int j = 0; j < 4; ++j) {
#pragma unroll
      for (int r = 0; r < 4; ++r) {
        const int n = n0 + wc * 64 + j * 16 + g * 4 + r;
        const int h = n >> 6, hd = n & 63;
        const float bn = bias[n];
#pragma unroll
        for (int i = 0; i < 4; ++i) {
          const int m = m0 + wr * 64 + i * 16 + c;
          const int bb = m >> 11, s = m & (S - 1);
          dst[((bb * H + h) * HD + hd) * S + s] = f2b(acc[i][j][r] + bn);
        }
      }
    }
  } else {
#pragma unroll
    for (int i = 0; i < 4; ++i) {
#pragma unroll
      for (int j = 0; j < 4; ++j) {
        const int n = n0 + wc * 64 + j * 16 + c;
        const int h = n >> 6, hd = n & 63;
        const float bn = bias[n];
#pragma unroll
        for (int r = 0; r < 4; ++r) {
          const int m = m0 + wr * 64 + i * 16 + g * 4 + r;
          const int bb = m >> 11, s = m & (S - 1);
          dst[((bb * H + h) * S + s) * HD + hd] = f2b(acc[i][j][r] + bn);
        }
      }
    }
  }
}

// ---------------- output GEMM: Out = att @ Wo^T + bo (fp32 out) ----------------
__global__ __launch_bounds__(256) void out_gemm(
    const short* __restrict__ Am, const short* __restrict__ W,
    const float* __restrict__ bias, float* __restrict__ Out) {
  const int tm = blockIdx.x & 63;
  const int tn = blockIdx.x >> 6;
  const int m0 = tm * 128, n0 = tn * 128;
  const int t = threadIdx.x;
  const int lane = t & 63, w = t >> 6;
  const int g = lane >> 4, c = lane & 15;
  const int wr = w >> 1, wc = w & 1;

  __shared__ __align__(16) short SM[4][2 * 128 * 32];  // 64 KB

  f32x4 acc[4][4];
  const f32x4 fz = {0.f, 0.f, 0.f, 0.f};
#pragma unroll
  for (int i = 0; i < 4; ++i)
#pragma unroll
    for (int j = 0; j < 4; ++j) acc[i][j] = fz;

  const short* Asrc0 = Am + (m0 + w * 16 + (lane >> 2)) * DMODEL + (lane & 3) * 8;
  const short* Asrc1 = Asrc0 + 64 * DMODEL;
  const short* Bsrc0 = W + (n0 + w * 16 + (lane >> 2)) * DMODEL + (lane & 3) * 8;
  const short* Bsrc1 = Bsrc0 + 64 * DMODEL;

#pragma unroll
  for (int tt = 0; tt < 3; ++tt) {
    glds16(Asrc0 + tt * 32, &SM[tt][w * 512]);
    glds16(Asrc1 + tt * 32, &SM[tt][2048 + w * 512]);
    glds16(Bsrc0 + tt * 32, &SM[tt][4096 + w * 512]);
    glds16(Bsrc1 + tt * 32, &SM[tt][4096 + 2048 + w * 512]);
  }

#pragma unroll 4
  for (int kt = 0; kt < 16; ++kt) {
    if (kt == 15) { WAIT_VM(0); } else if (kt == 14) { WAIT_VM(4); } else { WAIT_VM(8); }
    __builtin_amdgcn_s_barrier();
    SCHEDB();
    if (kt < 13) {
      const int k0 = (kt + 3) * 32;
      glds16(Asrc0 + k0, &SM[(kt + 3) & 3][w * 512]);
      glds16(Asrc1 + k0, &SM[(kt + 3) & 3][2048 + w * 512]);
      glds16(Bsrc0 + k0, &SM[(kt + 3) & 3][4096 + w * 512]);
      glds16(Bsrc1 + k0, &SM[(kt + 3) & 3][4096 + 2048 + w * 512]);
    }
    SCHEDB();

    bf16x8 af[4], bfr[4];
#pragma unroll
    for (int i = 0; i < 4; ++i)
      af[i] = *(const bf16x8*)&SM[kt & 3][(wr * 64 + i * 16 + c) * 32 + g * 8];
#pragma unroll
    for (int j = 0; j < 4; ++j)
      bfr[j] = *(const bf16x8*)&SM[kt & 3][4096 + (wc * 64 + j * 16 + c) * 32 + g * 8];
#pragma unroll
    for (int i = 0; i < 4; ++i)
#pragma unroll
      for (int j = 0; j < 4; ++j)
        acc[i][j] = MFMA16(af[i], bfr[j], acc[i][j]);
  }

#pragma unroll
  for (int i = 0; i < 4; ++i) {
#pragma unroll
    for (int j = 0; j < 4; ++j) {
      const int n = n0 + wc * 64 + j * 16 + c;
      const float bn = bias[n];
#pragma unroll
      for (int r = 0; r < 4; ++r) {
        const int m = m0 + wr * 64 + i * 16 + g * 4 + r;
        Out[m * DMODEL + n] = acc[i][j][r] + bn;
      }
    }
  }
}

// ---------------- flash attention: 8 waves = 4 q-subtiles x 2 kv-halves (R17/R19-proven) ----------------
__global__ __launch_bounds__(512, 4) void attn_kernel(
    const short* __restrict__ Qp, const short* __restrict__ Kp,
    const short* __restrict__ VTp, short* __restrict__ att) {
  const int bid = blockIdx.x;
  const int swzb = (bid & 7) * 64 + (bid >> 3);  // bijective (512 % 8 == 0)
  const int qt = swzb & 15;
  const int bh = swzb >> 4;
  const int b = bh >> 3, h = bh & 7;
  const short* Q  = Qp  + bh * (S * HD);
  const char*  Kg = (const char*)(Kp  + bh * (S * HD));
  const char*  Vg = (const char*)(VTp + bh * (HD * S));

  const int t = threadIdx.x;
  const int lane = t & 63, w = t >> 6;   // w 0..7
  const int qi = w >> 1, sj = w & 1;
  const int l31 = lane & 31, hi = lane >> 5;
  const int q0 = qt * 128 + qi * 32;

  __shared__ __align__(16) char smem[2 * 32768];  // [buf][K 16KB | V^T 16KB]

  // K staging (paired-row layout inverse)
  const char* ksrc[2];
#pragma unroll
  for (int j = 0; j < 2; ++j) {
    const int rj = w * 8 + j * 4 + (lane >> 4);
    const int tk = (lane & 15) ^ (rj & 15);
    const int kj = 2 * rj + (tk >> 3);
    ksrc[j] = Kg + kj * 128 + (tk & 7) * 16;
  }
  // V^T staging
  const char* vsrc[2];
#pragma unroll
  for (int j = 0; j < 2; ++j) {
    const int row = w * 8 + j * 4 + (lane >> 4);
    vsrc[j] = Vg + row * 4096 + (((lane & 15) ^ (row & 15)) * 16);
  }

  bf16x8 qf[4];
#pragma unroll
  for (int ks = 0; ks < 4; ++ks)
    qf[ks] = *(const bf16x8*)&Q[(q0 + l31) * HD + ks * 16 + hi * 8];

  f32x16 o0, o1, lsum, fz16;
#pragma unroll
  for (int i = 0; i < 16; ++i) { o0[i] = 0.f; o1[i] = 0.f; lsum[i] = 0.f; fz16[i] = 0.f; }

  const float SCL = 0.18033688011112042f;  // log2(e)/sqrt(HD)

  const int kbase = (l31 >> 1) * 256;
  const int k8 = (l31 & 1) << 3;
  const int kx = (l31 >> 1) & 15;
  const int vx = l31 & 15;
  const int sjb = sj * 8192;

  // prologue: stage tile 0 into buf 0 (4 glds/wave)
  {
    char* nb = smem;
#pragma unroll
    for (int j = 0; j < 2; ++j) glds16(ksrc[j], nb + w * 2048 + j * 1024);
#pragma unroll
    for (int j = 0; j < 2; ++j) glds16(vsrc[j], nb + 16384 + w * 2048 + j * 1024);
  }

  for (int kt = 0; kt < 16; ++kt) {
    WAIT_VM(0);  // tile kt landed
    __builtin_amdgcn_s_barrier();
    SCHEDB();
    if (kt < 15) {
      char* nb = smem + ((kt + 1) & 1) * 32768;
      const size_t ko = (size_t)(kt + 1) * 16384;
      const size_t vo = (size_t)(kt + 1) * 256;
#pragma unroll
      for (int j = 0; j < 2; ++j) glds16(ksrc[j] + ko, nb + w * 2048 + j * 1024);
#pragma unroll
      for (int j = 0; j < 2; ++j) glds16(vsrc[j] + vo, nb + 16384 + w * 2048 + j * 1024);
    }
    SCHEDB();

    const int cb = (kt & 1) * 32768;

    // ---- QK^T for this wave's kv-half ----
    f32x16 sA, sB;
    __builtin_amdgcn_s_setprio(1);
    {
      const int p0 = ((k8 | hi) ^ kx) * 16;
      sA = MFMA32(*(const bf16x8*)&smem[cb + sjb + kbase + p0],        qf[0], fz16);
      sB = MFMA32(*(const bf16x8*)&smem[cb + sjb + 4096 + kbase + p0], qf[0], fz16);
    }
#pragma unroll
    for (int ks = 1; ks < 4; ++ks) {
      const int p = ((k8 | (ks * 2 + hi)) ^ kx) * 16;
      sA = MFMA32(*(const bf16x8*)&smem[cb + sjb + kbase + p],        qf[ks], sA);
      sB = MFMA32(*(const bf16x8*)&smem[cb + sjb + 4096 + kbase + p], qf[ks], sB);
    }
    __builtin_amdgcn_s_setprio(0);

    // ---- P = exp2(score * SCL) ----
#pragma unroll
    for (int i = 0; i < 16; ++i) {
      sA[i] = rexp2(sA[i] * SCL);
      sB[i] = rexp2(sB[i] * SCL);
    }

    // ---- deferred denominator ----
#pragma unroll
    for (int i = 0; i < 16; ++i) lsum[i] += sA[i] + sB[i];

    // ---- P -> bf16 words ----
    unsigned int wrdA[8], wrdB[8];
#pragma unroll
    for (int i = 0; i < 8; ++i) {
      asm("v_cvt_pk_bf16_f32 %0, %1, %2" : "=v"(wrdA[i]) : "v"(sA[2 * i]), "v"(sA[2 * i + 1]));
      asm("v_cvt_pk_bf16_f32 %0, %1, %2" : "=v"(wrdB[i]) : "v"(sB[2 * i]), "v"(sB[2 * i + 1]));
    }

    // ---- PV over this kv-half ----
    __builtin_amdgcn_s_setprio(1);
#pragma unroll
    for (int ks = 0; ks < 4; ++ks) {
      const int ss = sj * 4 + ks;
      const int i0 = (ks & 1) * 4;
      const unsigned int* lo = (ks < 2) ? wrdA : wrdB;
      unsigned int a0 = lo[i0 + 0], b0 = lo[i0 + 2];
      unsigned int a1 = lo[i0 + 1], b1 = lo[i0 + 3];
      asm("v_permlane32_swap_b32 %0, %1" : "+v"(a0), "+v"(b0));
      asm("v_permlane32_swap_b32 %0, %1" : "+v"(a1), "+v"(b1));
      u32x4 fw;
      fw[0] = a0; fw[1] = a1; fw[2] = b0; fw[3] = b1;
      const bf16x8 pfrag = __builtin_bit_cast(bf16x8, fw);
      const int pv = ((ss * 2 + hi) ^ vx) * 16;
      const bf16x8 va0 = *(const bf16x8*)&smem[cb + 16384 + l31 * 256 + pv];
      const bf16x8 va1 = *(const bf16x8*)&smem[cb + 16384 + (32 + l31) * 256 + pv];
      o0 = MFMA32(va0, pfrag, o0);
      o1 = MFMA32(va1, pfrag, o1);
    }
    __builtin_amdgcn_s_setprio(0);
  }

  // ---- finalize denominator ----
  float ts[8];
#pragma unroll
  for (int i = 0; i < 8; ++i) ts[i] = lsum[i] + lsum[i + 8];
#pragma unroll
  for (int i = 0; i < 4; ++i) ts[i] = ts[i] + ts[i + 4];
  float lst = (ts[0] + ts[2]) + (ts[1] + ts[3]);
  lst += __shfl_xor(lst, 32, 64);

  // ---- merge kv-halves (pure sum) ----
  __syncthreads();
  float* mrg = (float*)smem;
  if (sj == 1) {
    float* p = mrg + (qi * 64 + lane) * 33;
#pragma unroll
    for (int i = 0; i < 16; ++i) { p[i] = o0[i]; p[16 + i] = o1[i]; }
    p[32] = lst;
  }
  __syncthreads();
  if (sj == 0) {
    const float* p = mrg + (qi * 64 + lane) * 33;
    const float inv = 1.0f / (lst + p[32]);
    short* arow = att + (b * S + q0 + l31) * DMODEL + h * HD;
#pragma unroll
    for (int dt = 0; dt < 2; ++dt) {
#pragma unroll
      for (int rr = 0; rr < 4; ++rr) {
        const int i0 = 4 * rr;
        const float* po = p + dt * 16;
        float v0 = ((dt ? o1[i0 + 0] : o0[i0 + 0]) + po[i0 + 0]) * inv;
        float v1 = ((dt ? o1[i0 + 1] : o0[i0 + 1]) + po[i0 + 1]) * inv;
        float v2 = ((dt ? o1[i0 + 2] : o0[i0 + 2]) + po[i0 + 2]) * inv;
        float v3 = ((dt ? o1[i0 + 3] : o0[i0 + 3]) + po[i0 + 3]) * inv;
        unsigned int w0, w1;
        asm("v_cvt_pk_bf16_f32 %0, %1, %2" : "=v"(w0) : "v"(v0), "v"(v1));
        asm("v_cvt_pk_bf16_f32 %0, %1, %2" : "=v"(w1) : "v"(v2), "v"(v3));
        uint2 pk2;
        pk2.x = w0; pk2.y = w1;
        *(uint2*)&arow[dt * 32 + rr * 8 + hi * 4] = pk2;
      }
    }
  }
}

extern "C" void kernel_launch(void* const* d_in, const int* in_sizes, int n_in,
                              void* d_out, int out_size, void* d_ws, size_t ws_size,
                              hipStream_t stream) {
  const float* query = (const float*)d_in[0];
  const float* key_  = (const float*)d_in[1];
  const float* value = (const float*)d_in[2];
  const float* Wq = (const float*)d_in[3];
  const float* bq = (const float*)d_in[4];
  const float* Wk = (const float*)d_in[5];
  const float* bk = (const float*)d_in[6];
  const float* Wv = (const float*)d_in[7];
  const float* bv = (const float*)d_in[8];
  const float* Wo = (const float*)d_in[9];
  const float* bo = (const float*)d_in[10];
  float* out = (float*)d_out;

  char* ws = (char*)d_ws;
  const size_t WB_BYTES  = (size_t)4 * DMODEL * DMODEL * 2;  // 2 MiB
  const size_t MAT_BYTES = (size_t)M * DMODEL * 2;           // 8 MiB each
  short* Wb  = (short*)ws;
  short* Qp  = (short*)(ws + WB_BYTES);
  short* Kp  = (short*)(ws + WB_BYTES + MAT_BYTES);
  short* Vp  = (short*)(ws + WB_BYTES + 2 * MAT_BYTES);   // transposed [B,H,HD,S]
  short* att = (short*)(ws + WB_BYTES + 3 * MAT_BYTES);
  short* Abq = (short*)(ws + WB_BYTES + 4 * MAT_BYTES);
  short* Abk = (short*)(ws + WB_BYTES + 5 * MAT_BYTES);
  short* Abv = att;  // alias: Abv consumed by proj before attn writes att

  convert_all<<<dim3(6656), 256, 0, stream>>>(query, key_, value, Wq, Wk, Wv, Wo,
                                              Abq, Abk, Abv, Wb);
  proj_gemm<<<dim3(256, 3), 256, 0, stream>>>(Abq, Abk, Abv, Wb, bq, bk, bv, Qp, Kp, Vp);
  attn_kernel<<<dim3(512), 512, 0, stream>>>(Qp, Kp, Vp, att);
  out_gemm<<<dim3(256), 256, 0, stream>>>(att, Wb + 3 * DMODEL * DMODEL, bo, out);
}